// Round 11
// baseline (134.630 us; speedup 1.0000x reference)
//
#include <hip/hip_runtime.h>
#include <hip/hip_cooperative_groups.h>
#include <math.h>

// Chamfer distance, B=4, N=M=8192, D=3, fp32 — single cooperative kernel.
//
// t = q.r - c_r via v_mfma_f32_32x32x16_f16, fp16 hi/lo split (HW-verified
// rounds 9/10, absmax 0.0):
//   A (ref):   k0..7 = [h0,h1,h2,l0,l1,l2,h0,h1], k8..15 = [h2,-chi,-clo,0..]
//   B (query): k0..7 = [hq0,hq1,hq2,hq0,hq1,hq2,lq0,lq1], k8..15 = [lq2,1,1,0..]
//   dot = (h+l).(hq+lq) - l.lq - c   (|l.lq| <= ~3e-6)
// min_r d^2/2 = cq - max_r t.  A row = lane&31, k-half = lane>>5;
// C col = lane&31, row = (reg&3)+8*(reg>>2)+4*(lane>>5) -> shfl_xor(32) fold.
//
// Round-11 structure: 128 queries/wave (4 B-frags per A-tile ds_read) ->
// DS traffic /4 vs round 10 (was the 10 us/CU floor); VALU merge
// (8 v_max3 per MFMA, 8192 cyc/SIMD = 3.4 us) is the new floor.
// MSPLIT=4 ref slices keep grid at 256 blocks = 1/CU (co-resident), so
// hipLaunchCooperativeKernel + grid.sync() does partial-min combine, sqrt,
// mean and the final sum IN-kernel (plain store to *out, no memset node).
// Graph = 1 node. ~40 us of dur_us is the harness 0xAA re-poison of the
// 256 MB ws (fillBufferAligned) — uncontrollable floor.

namespace cg = cooperative_groups;

typedef __attribute__((ext_vector_type(8)))  _Float16 f16x8;
typedef __attribute__((ext_vector_type(16))) float    f32x16;

constexpr int TPB   = 512;            // 8 waves
constexpr int NPTS  = 8192;           // N == M
constexpr int NB    = 4;              // batch
constexpr int MS    = 4;              // ref slices
constexpr int SLICE = NPTS / MS;      // 2048 refs per block
constexpr int CHUNK = 512;            // refs per LDS buffer
constexpr int NCH   = SLICE / CHUNK;  // 4
constexpr int TILES = CHUNK / 32;     // 16 MFMA ref-tiles per chunk
constexpr int QPW   = 128;            // queries per wave (4 col-frags)
constexpr int QPB   = TPB / 64 * QPW; // 1024 queries per block
constexpr int NSLOT = 2 * NB * NPTS;  // 65536 (dir,b,q) slots

__device__ inline float max3f(float a, float b, float c) {
    return fmaxf(fmaxf(a, b), c);   // clang fuses to v_max3_f32
}

__device__ inline float merge16(float run, f32x16 v) {
    const float w0 = max3f(v[0],  v[1],  v[2]);
    const float w1 = max3f(v[3],  v[4],  v[5]);
    const float w2 = max3f(v[6],  v[7],  v[8]);
    const float w3 = max3f(v[9],  v[10], v[11]);
    const float w4 = max3f(v[12], v[13], v[14]);
    const float x0 = max3f(w0, w1, v[15]);
    const float x1 = max3f(w2, w3, w4);
    return max3f(run, x0, x1);
}

__device__ inline f16x8 make_qfrag(float x, float y, float z, int half) {
    const _Float16 hx = (_Float16)x, hy = (_Float16)y, hz = (_Float16)z;
    const _Float16 lx = (_Float16)(x - (float)hx);
    const _Float16 ly = (_Float16)(y - (float)hy);
    const _Float16 lz = (_Float16)(z - (float)hz);
    const f16x8 f0 = (f16x8){hx, hy, hz, hx, hy, hz, lx, ly};
    const f16x8 f1 = (f16x8){lz, (_Float16)1.0f, (_Float16)1.0f, 0, 0, 0, 0, 0};
    return half ? f1 : f0;
}

// Convert one ref point -> both A-fragments at chunk-local index r.
// r = tid: per-wave lanes 0..31 / 32..63 each write a linear 512B run.
__device__ inline void write_ref(f16x8* buf, int r, float x, float y, float z) {
    const _Float16 hx = (_Float16)x, hy = (_Float16)y, hz = (_Float16)z;
    const _Float16 lx = (_Float16)(x - (float)hx);
    const _Float16 ly = (_Float16)(y - (float)hy);
    const _Float16 lz = (_Float16)(z - (float)hz);
    const float c = 0.5f * fmaf(z, z, fmaf(y, y, x * x));
    const _Float16 chi = (_Float16)c;
    const _Float16 clo = (_Float16)(c - (float)chi);
    const int base = (r >> 5) * 64 + (r & 31);
    buf[base]      = (f16x8){hx, hy, hz, lx, ly, lz, hx, hy};
    buf[base + 32] = (f16x8){hz, -chi, -clo, 0, 0, 0, 0, 0};
}

__global__ __launch_bounds__(TPB) void chamfer_coop(
    const float* __restrict__ inp, const float* __restrict__ tgt,
    float* __restrict__ pmin,      // [MS][NSLOT] partial d^2/2
    float* __restrict__ bsum,      // [256] per-block sums
    float* __restrict__ out)
{
    const int gid   = blockIdx.x;        // 0..255
    const int slice = gid & (MS - 1);
    const int qb    = gid >> 2;          // 0..63
    const int z     = qb >> 3;           // dir*4 + b
    const int qt    = qb & 7;            // query tile within (dir,b)
    const int dir   = z >> 2, b = z & 3;
    const float* Q = (dir ? tgt : inp) + (size_t)b * NPTS * 3;
    const float* R = (dir ? inp : tgt) + (size_t)b * NPTS * 3;

    const int tid  = threadIdx.x;
    const int w    = tid >> 6;
    const int lane = tid & 63;
    const int half = lane >> 5;
    const int col  = lane & 31;

    // 4 query column-fragments per wave (128 queries/wave)
    float qx[4], qy[4], qz[4];
    f16x8 bq[4];
#pragma unroll
    for (int f = 0; f < 4; ++f) {
        const int q = qt * QPB + w * QPW + f * 32 + col;
        qx[f] = Q[q * 3 + 0]; qy[f] = Q[q * 3 + 1]; qz[f] = Q[q * 3 + 2];
        bq[f] = make_qfrag(qx[f], qy[f], qz[f], half);
    }

    __shared__ f16x8 lds[2 * 1024];      // dbuf: 2 x 512 refs x 32B = 32 KB
    const float* rbase = R + (size_t)slice * SLICE * 3;

    {   // prologue: stage chunk 0 (1 ref per thread)
        const float* s = rbase + (size_t)tid * 3;
        write_ref(lds, tid, s[0], s[1], s[2]);
    }
    __syncthreads();

    const f32x16 zf = (f32x16)0.0f;      // persistent zero C-operand
    float run[4] = {-3.4e38f, -3.4e38f, -3.4e38f, -3.4e38f};

    for (int c = 0; c < NCH; ++c) {
        f16x8* bufR = lds + (c & 1) * 1024;
        f16x8* bufW = lds + ((c & 1) ^ 1) * 1024;

        float nx = 0, ny = 0, nz = 0;
        const bool more = (c + 1 < NCH);
        if (more) {   // issue next chunk's loads early (latency under MFMA)
            const float* s = rbase + (size_t)((c + 1) * CHUNK + tid) * 3;
            nx = s[0]; ny = s[1]; nz = s[2];
        }

#pragma unroll 4
        for (int t = 0; t < TILES; ++t) {
            const f16x8 a = bufR[t * 64 + lane];   // linear ds_read_b128
#pragma unroll
            for (int f = 0; f < 4; ++f) {
                const f32x16 acc =
                    __builtin_amdgcn_mfma_f32_32x32x16_f16(a, bq[f], zf, 0, 0, 0);
                run[f] = merge16(run[f], acc);
            }
        }

        if (more) write_ref(bufW, tid, nx, ny, nz);
        __syncthreads();
    }

    // fold k-halves (lanes l, l^32 hold complementary ref rows), store partial
#pragma unroll
    for (int f = 0; f < 4; ++f) {
        run[f] = fmaxf(run[f], __shfl_xor(run[f], 32));
        if (lane < 32) {
            const float cq = 0.5f * fmaf(qz[f], qz[f],
                                fmaf(qy[f], qy[f], qx[f] * qx[f]));
            pmin[(size_t)slice * NSLOT + z * NPTS
                 + qt * QPB + w * QPW + f * 32 + col]
                = fmaxf(cq - run[f], 0.0f);
        }
    }

    cg::this_grid().sync();

    __shared__ float bs[8];
    {   // phase 2: min over slices, sqrt, mean; per-block sum
        const int i = gid * TPB + tid;   // 0..131071; work on first 65536
        float term = 0.0f;
        if (i < NSLOT) {
            float v = pmin[i];
#pragma unroll
            for (int sl = 1; sl < MS; ++sl)
                v = fminf(v, pmin[(size_t)sl * NSLOT + i]);
            term = sqrtf(2.0f * v) * (1.0f / NPTS);
        }
#pragma unroll
        for (int off = 32; off > 0; off >>= 1) term += __shfl_down(term, off, 64);
        if (lane == 0) bs[w] = term;
        __syncthreads();
        if (tid == 0) {
            float s = 0.0f;
#pragma unroll
            for (int j = 0; j < 8; ++j) s += bs[j];
            bsum[gid] = s;
        }
    }

    cg::this_grid().sync();

    if (gid == 0) {   // phase 3: final 256-way sum, plain store
        float v = (tid < 256) ? bsum[tid] : 0.0f;
#pragma unroll
        for (int off = 32; off > 0; off >>= 1) v += __shfl_down(v, off, 64);
        __shared__ float bs2[8];
        if (lane == 0) bs2[w] = v;
        __syncthreads();
        if (tid == 0) {
            float s = 0.0f;
#pragma unroll
            for (int j = 0; j < 8; ++j) s += bs2[j];
            *out = s;
        }
    }
}

// ---- fallback (proven round-3 VALU path, general shapes) ----
__global__ __launch_bounds__(256) void chamfer_nn_valu(
    const float* __restrict__ A, const float* __restrict__ Bp,
    unsigned int* __restrict__ minA, unsigned int* __restrict__ minB,
    int N, int M, int B)
{
    const int bz = blockIdx.z, b = bz % B, dir = bz / B;
    const float* Q = dir ? Bp : A;
    const float* R = dir ? A : Bp;
    unsigned int* om = dir ? minB : minA;
    const int NQ = dir ? M : N, NR = dir ? N : M;
    const int mSlice = NR / gridDim.y;
    const int tid = threadIdx.x;
    const int nBase = blockIdx.x * (256 * 4);
    const int mStart = blockIdx.y * mSlice;
    const float* qb = Q + (size_t)b * NQ * 3;
    const float* rb = R + (size_t)b * NR * 3;
    float qx[4], qy[4], qz[4], dmax[4];
#pragma unroll
    for (int k = 0; k < 4; ++k) {
        const int n = nBase + tid + k * 256;
        qx[k] = qb[n * 3]; qy[k] = qb[n * 3 + 1]; qz[k] = qb[n * 3 + 2];
        dmax[k] = -3.4e38f;
    }
    __shared__ float4 tgtl[256];
    for (int m0 = mStart; m0 < mStart + mSlice; m0 += 256) {
        __syncthreads();
        {
            const float* src = rb + (size_t)(m0 + tid) * 3;
            const float rx = src[0], ry = src[1], rz = src[2];
            tgtl[tid] = make_float4(rx, ry, rz,
                -0.5f * fmaf(rz, rz, fmaf(ry, ry, rx * rx)));
        }
        __syncthreads();
#pragma unroll 2
        for (int j = 0; j < 256; j += 2) {
            const float4 r0 = tgtl[j], r1 = tgtl[j + 1];
#pragma unroll
            for (int k = 0; k < 4; ++k) {
                const float t0 = fmaf(qz[k], r0.z, fmaf(qy[k], r0.y, fmaf(qx[k], r0.x, r0.w)));
                const float t1 = fmaf(qz[k], r1.z, fmaf(qy[k], r1.y, fmaf(qx[k], r1.x, r1.w)));
                dmax[k] = max3f(dmax[k], t0, t1);
            }
        }
    }
#pragma unroll
    for (int k = 0; k < 4; ++k) {
        const int n = nBase + tid + k * 256;
        const float c = 0.5f * fmaf(qz[k], qz[k], fmaf(qy[k], qy[k], qx[k] * qx[k]));
        atomicMin(&om[(size_t)b * NQ + n], __float_as_uint(fmaxf(c - dmax[k], 0.0f)));
    }
}

__global__ __launch_bounds__(256) void chamfer_reduce(
    const unsigned int* __restrict__ mins, int nA, int nTotal,
    float scaleA, float scaleB, float* __restrict__ out)
{
    float s = 0.0f;
    for (int i = blockIdx.x * blockDim.x + threadIdx.x; i < nTotal;
         i += gridDim.x * blockDim.x) {
        s += sqrtf(2.0f * __uint_as_float(mins[i])) * (i < nA ? scaleA : scaleB);
    }
#pragma unroll
    for (int off = 32; off > 0; off >>= 1) s += __shfl_down(s, off, 64);
    __shared__ float wsum[4];
    const int lane = threadIdx.x & 63, wid = threadIdx.x >> 6;
    if (lane == 0) wsum[wid] = s;
    __syncthreads();
    if (threadIdx.x == 0) atomicAdd(out, wsum[0] + wsum[1] + wsum[2] + wsum[3]);
}

extern "C" void kernel_launch(void* const* d_in, const int* in_sizes, int n_in,
                              void* d_out, int out_size, void* d_ws, size_t ws_size,
                              hipStream_t stream) {
    const float* inp = (const float*)d_in[0];  // [B, N, 3]
    const float* tgt = (const float*)d_in[1];  // [B, M, 3]
    float* out = (float*)d_out;

    const int B = 4, D = 3;
    const int N = in_sizes[0] / (B * D);
    const int M = in_sizes[1] / (B * D);

    const size_t needBytes = (size_t)(MS * NSLOT + 256) * sizeof(float); // ~1 MB

    if (N == NPTS && M == NPTS && B == NB && ws_size >= needBytes) {
        // ---- cooperative fused path: ONE graph node ----
        float* pmin = (float*)d_ws;
        float* bsum = pmin + (size_t)MS * NSLOT;
        void* args[] = {(void*)&inp, (void*)&tgt, (void*)&pmin,
                        (void*)&bsum, (void*)&out};
        hipLaunchCooperativeKernel((void*)chamfer_coop, dim3(256), dim3(TPB),
                                   args, 0, stream);
    } else {
        // ---- fallback: proven sentinel/atomic VALU path ----
        unsigned int* min_in  = (unsigned int*)d_ws;
        unsigned int* min_tgt = min_in + (size_t)B * N;
        hipMemsetAsync(d_ws, 0xFF,
                       (size_t)(B * N + B * M) * sizeof(unsigned int), stream);
        hipMemsetAsync(d_out, 0, sizeof(float), stream);
        dim3 grid(N / (256 * 4), 32, 2 * B);
        chamfer_nn_valu<<<grid, 256, 0, stream>>>(inp, tgt, min_in, min_tgt, N, M, B);
        chamfer_reduce<<<dim3(64), 256, 0, stream>>>(
            min_in, B * N, B * (N + M), 1.0f / N, 1.0f / M, out);
    }
}

// Round 12
// 86.035 us; speedup vs baseline: 1.5648x; 1.5648x over previous
//
#include <hip/hip_runtime.h>
#include <math.h>

// Chamfer distance, B=4, N=M=8192, D=3, fp32 — MFMA, occupancy-first.
//
// t = q.r - c_r via v_mfma_f32_32x32x16_f16, fp16 hi/lo split (HW-verified
// rounds 9/10, absmax 0.0):
//   A (ref):   k0..7 = [h0,h1,h2,l0,l1,l2,h0,h1], k8..15 = [h2,-chi,-clo,0..]
//   B (query): k0..7 = [hq0,hq1,hq2,hq0,hq1,hq2,lq0,lq1], k8..15 = [lq2,1,1,0..]
//   dot = (h+l).(hq+lq) - l.lq - c   (|l.lq| <= ~3e-6)
// min_r d^2/2 = cq - max_r t.  A row = lane&31, k-half = lane>>5;
// C col = lane&31, row = (reg&3)+8*(reg>>2)+4*(lane>>5) -> shfl_xor(32) fold.
//
// Round-11 lesson: cooperative 256-block layout = 2 waves/SIMD = latency-
// bound (MfmaUtil 10%, VALUBusy 13%, 63.7 us). This round: MS=16 slices ->
// 2048 blocks x 4 waves (up to 32 waves/CU) so MFMA/LDS latency hides
// behind other waves. 128 queries/wave keeps the DS amortization (1
// ds_read_b128 feeds 4 MFMA). Single 512-ref LDS chunk per block (16 KB),
// one barrier, no double buffering needed.
// ~40 us of dur_us is the harness 0xAA re-poison of the 256 MB ws — floor.

typedef __attribute__((ext_vector_type(8)))  _Float16 f16x8;
typedef __attribute__((ext_vector_type(16))) float    f32x16;

constexpr int TPB   = 256;            // 4 waves
constexpr int NPTS  = 8192;           // N == M
constexpr int NB    = 4;              // batch
constexpr int MS    = 16;             // ref slices
constexpr int SLICE = NPTS / MS;      // 512 refs per block
constexpr int TILES = SLICE / 32;     // 16 MFMA ref-tiles
constexpr int QPW   = 128;            // queries per wave (4 col-frags)
constexpr int QPB   = TPB / 64 * QPW; // 512 queries per block
constexpr int NSLOT = 2 * NB * NPTS;  // 65536 (dir,b,q) slots

__device__ inline float max3f(float a, float b, float c) {
    return fmaxf(fmaxf(a, b), c);   // clang fuses to v_max3_f32
}

__device__ inline float merge16(float run, f32x16 v) {
    const float w0 = max3f(v[0],  v[1],  v[2]);
    const float w1 = max3f(v[3],  v[4],  v[5]);
    const float w2 = max3f(v[6],  v[7],  v[8]);
    const float w3 = max3f(v[9],  v[10], v[11]);
    const float w4 = max3f(v[12], v[13], v[14]);
    const float x0 = max3f(w0, w1, v[15]);
    const float x1 = max3f(w2, w3, w4);
    return max3f(run, x0, x1);
}

__device__ inline f16x8 make_qfrag(float x, float y, float z, int half) {
    const _Float16 hx = (_Float16)x, hy = (_Float16)y, hz = (_Float16)z;
    const _Float16 lx = (_Float16)(x - (float)hx);
    const _Float16 ly = (_Float16)(y - (float)hy);
    const _Float16 lz = (_Float16)(z - (float)hz);
    const f16x8 f0 = (f16x8){hx, hy, hz, hx, hy, hz, lx, ly};
    const f16x8 f1 = (f16x8){lz, (_Float16)1.0f, (_Float16)1.0f, 0, 0, 0, 0, 0};
    return half ? f1 : f0;
}

// Convert one ref point -> both A-fragments at chunk-local index r.
// Lanes within a wave write linear 512B runs -> conflict-free ds_write_b128.
__device__ inline void write_ref(f16x8* buf, int r, float x, float y, float z) {
    const _Float16 hx = (_Float16)x, hy = (_Float16)y, hz = (_Float16)z;
    const _Float16 lx = (_Float16)(x - (float)hx);
    const _Float16 ly = (_Float16)(y - (float)hy);
    const _Float16 lz = (_Float16)(z - (float)hz);
    const float c = 0.5f * fmaf(z, z, fmaf(y, y, x * x));
    const _Float16 chi = (_Float16)c;
    const _Float16 clo = (_Float16)(c - (float)chi);
    const int base = (r >> 5) * 64 + (r & 31);
    buf[base]      = (f16x8){hx, hy, hz, lx, ly, lz, hx, hy};
    buf[base + 32] = (f16x8){hz, -chi, -clo, 0, 0, 0, 0, 0};
}

__global__ __launch_bounds__(TPB) void chamfer_nn_mfma(
    const float* __restrict__ inp, const float* __restrict__ tgt,
    float* __restrict__ pmin)          // [MS][NSLOT] partial d^2/2
{
    const int qb    = blockIdx.x;      // 0..127 query block
    const int slice = blockIdx.y;      // 0..15 ref slice
    const int z     = qb >> 4;         // dir*4 + b
    const int qt    = qb & 15;         // query tile (512 queries)
    const int dir   = z >> 2, b = z & 3;
    const float* Q = (dir ? tgt : inp) + (size_t)b * NPTS * 3;
    const float* R = (dir ? inp : tgt) + (size_t)b * NPTS * 3;

    const int tid  = threadIdx.x;
    const int w    = tid >> 6;
    const int lane = tid & 63;
    const int half = lane >> 5;
    const int col  = lane & 31;

    __shared__ f16x8 lds[2 * SLICE];   // 512 refs x 2 frags x 16B = 16 KB

    {   // stage this slice's 512 refs (2 per thread), convert in-kernel
        const float* s0 = R + (size_t)(slice * SLICE + tid) * 3;
        const float* s1 = R + (size_t)(slice * SLICE + TPB + tid) * 3;
        const float a0 = s0[0], a1 = s0[1], a2 = s0[2];
        const float b0 = s1[0], b1 = s1[1], b2 = s1[2];
        write_ref(lds, tid,       a0, a1, a2);
        write_ref(lds, TPB + tid, b0, b1, b2);
    }

    // 4 query column-fragments per wave (128 queries/wave); keep only
    // cq + packed frags in registers (round-5 lesson: watch VGPR count)
    float cq[4];
    f16x8 bq[4];
#pragma unroll
    for (int f = 0; f < 4; ++f) {
        const int q = qt * QPB + w * QPW + f * 32 + col;
        const float x = Q[q * 3 + 0], y = Q[q * 3 + 1], zc = Q[q * 3 + 2];
        cq[f] = 0.5f * fmaf(zc, zc, fmaf(y, y, x * x));
        bq[f] = make_qfrag(x, y, zc, half);
    }

    __syncthreads();

    const f32x16 zf = (f32x16)0.0f;    // persistent zero C-operand
    float run[4] = {-3.4e38f, -3.4e38f, -3.4e38f, -3.4e38f};

#pragma unroll 2
    for (int t = 0; t < TILES; ++t) {
        const f16x8 a = lds[t * 64 + lane];   // linear ds_read_b128, 1:4 MFMA
#pragma unroll
        for (int f = 0; f < 4; ++f) {
            const f32x16 acc =
                __builtin_amdgcn_mfma_f32_32x32x16_f16(a, bq[f], zf, 0, 0, 0);
            run[f] = merge16(run[f], acc);
        }
    }

    // fold k-halves (lanes l, l^32 hold complementary ref rows)
#pragma unroll
    for (int f = 0; f < 4; ++f) {
        run[f] = fmaxf(run[f], __shfl_xor(run[f], 32));
        if (lane < 32) {
            pmin[(size_t)slice * NSLOT + (size_t)z * NPTS
                 + qt * QPB + w * QPW + f * 32 + col]
                = fmaxf(cq[f] - run[f], 0.0f);
        }
    }
}

// min over MS slices per slot, sqrt, mean, sum.
__global__ __launch_bounds__(256) void reduce_mfma(
    const float* __restrict__ pmin, float* __restrict__ out, float inv)
{
    const int i = blockIdx.x * 256 + threadIdx.x;   // 0..65535
    float v = pmin[i];
#pragma unroll
    for (int sl = 1; sl < MS; ++sl)
        v = fminf(v, pmin[(size_t)sl * NSLOT + i]);
    float term = sqrtf(2.0f * v) * inv;
#pragma unroll
    for (int off = 32; off > 0; off >>= 1) term += __shfl_down(term, off, 64);
    __shared__ float wsum[4];
    const int lane = threadIdx.x & 63, wid = threadIdx.x >> 6;
    if (lane == 0) wsum[wid] = term;
    __syncthreads();
    if (threadIdx.x == 0) atomicAdd(out, wsum[0] + wsum[1] + wsum[2] + wsum[3]);
}

// ---- fallback (proven round-3 VALU path, general shapes) ----
__global__ __launch_bounds__(256) void chamfer_nn_valu(
    const float* __restrict__ A, const float* __restrict__ Bp,
    unsigned int* __restrict__ minA, unsigned int* __restrict__ minB,
    int N, int M, int B)
{
    const int bz = blockIdx.z, b = bz % B, dir = bz / B;
    const float* Q = dir ? Bp : A;
    const float* R = dir ? A : Bp;
    unsigned int* om = dir ? minB : minA;
    const int NQ = dir ? M : N, NR = dir ? N : M;
    const int mSlice = NR / gridDim.y;
    const int tid = threadIdx.x;
    const int nBase = blockIdx.x * (256 * 4);
    const int mStart = blockIdx.y * mSlice;
    const float* qb = Q + (size_t)b * NQ * 3;
    const float* rb = R + (size_t)b * NR * 3;
    float qx[4], qy[4], qz[4], dmax[4];
#pragma unroll
    for (int k = 0; k < 4; ++k) {
        const int n = nBase + tid + k * 256;
        qx[k] = qb[n * 3]; qy[k] = qb[n * 3 + 1]; qz[k] = qb[n * 3 + 2];
        dmax[k] = -3.4e38f;
    }
    __shared__ float4 tgtl[256];
    for (int m0 = mStart; m0 < mStart + mSlice; m0 += 256) {
        __syncthreads();
        {
            const float* src = rb + (size_t)(m0 + tid) * 3;
            const float rx = src[0], ry = src[1], rz = src[2];
            tgtl[tid] = make_float4(rx, ry, rz,
                -0.5f * fmaf(rz, rz, fmaf(ry, ry, rx * rx)));
        }
        __syncthreads();
#pragma unroll 2
        for (int j = 0; j < 256; j += 2) {
            const float4 r0 = tgtl[j], r1 = tgtl[j + 1];
#pragma unroll
            for (int k = 0; k < 4; ++k) {
                const float t0 = fmaf(qz[k], r0.z, fmaf(qy[k], r0.y, fmaf(qx[k], r0.x, r0.w)));
                const float t1 = fmaf(qz[k], r1.z, fmaf(qy[k], r1.y, fmaf(qx[k], r1.x, r1.w)));
                dmax[k] = max3f(dmax[k], t0, t1);
            }
        }
    }
#pragma unroll
    for (int k = 0; k < 4; ++k) {
        const int n = nBase + tid + k * 256;
        const float c = 0.5f * fmaf(qz[k], qz[k], fmaf(qy[k], qy[k], qx[k] * qx[k]));
        atomicMin(&om[(size_t)b * NQ + n], __float_as_uint(fmaxf(c - dmax[k], 0.0f)));
    }
}

__global__ __launch_bounds__(256) void chamfer_reduce(
    const unsigned int* __restrict__ mins, int nA, int nTotal,
    float scaleA, float scaleB, float* __restrict__ out)
{
    float s = 0.0f;
    for (int i = blockIdx.x * blockDim.x + threadIdx.x; i < nTotal;
         i += gridDim.x * blockDim.x) {
        s += sqrtf(2.0f * __uint_as_float(mins[i])) * (i < nA ? scaleA : scaleB);
    }
#pragma unroll
    for (int off = 32; off > 0; off >>= 1) s += __shfl_down(s, off, 64);
    __shared__ float wsum[4];
    const int lane = threadIdx.x & 63, wid = threadIdx.x >> 6;
    if (lane == 0) wsum[wid] = s;
    __syncthreads();
    if (threadIdx.x == 0) atomicAdd(out, wsum[0] + wsum[1] + wsum[2] + wsum[3]);
}

extern "C" void kernel_launch(void* const* d_in, const int* in_sizes, int n_in,
                              void* d_out, int out_size, void* d_ws, size_t ws_size,
                              hipStream_t stream) {
    const float* inp = (const float*)d_in[0];  // [B, N, 3]
    const float* tgt = (const float*)d_in[1];  // [B, M, 3]
    float* out = (float*)d_out;

    const int B = 4, D = 3;
    const int N = in_sizes[0] / (B * D);
    const int M = in_sizes[1] / (B * D);

    const size_t needBytes = (size_t)MS * NSLOT * sizeof(float);  // 4 MB

    if (N == NPTS && M == NPTS && B == NB && ws_size >= needBytes) {
        // ---- MFMA path: 3 graph nodes ----
        float* pmin = (float*)d_ws;
        hipMemsetAsync(d_out, 0, sizeof(float), stream);
        dim3 grid(NSLOT / QPB, MS);            // (128, 16) = 2048 blocks
        chamfer_nn_mfma<<<grid, TPB, 0, stream>>>(inp, tgt, pmin);
        reduce_mfma<<<dim3(NSLOT / 256), 256, 0, stream>>>(
            pmin, out, 1.0f / NPTS);
    } else {
        // ---- fallback: proven sentinel/atomic VALU path ----
        unsigned int* min_in  = (unsigned int*)d_ws;
        unsigned int* min_tgt = min_in + (size_t)B * N;
        hipMemsetAsync(d_ws, 0xFF,
                       (size_t)(B * N + B * M) * sizeof(unsigned int), stream);
        hipMemsetAsync(d_out, 0, sizeof(float), stream);
        dim3 grid(N / (256 * 4), 32, 2 * B);
        chamfer_nn_valu<<<grid, 256, 0, stream>>>(inp, tgt, min_in, min_tgt, N, M, B);
        chamfer_reduce<<<dim3(64), 256, 0, stream>>>(
            min_in, B * N, B * (N + M), 1.0f / N, 1.0f / M, out);
    }
}